// Round 10
// baseline (153.198 us; speedup 1.0000x reference)
//
#include <hip/hip_runtime.h>
#include <math.h>

// Problem: scores = q[2048x768] @ p[16384x768]^T (fp32 in), per-query
// rank-of-target + log-softmax CE + Gaussian rank weight -> mean (scalar).
// R13 = R12 (counted-vmcnt triple-buffer, 60.3 us gemm, MfmaUtil 33%) with:
//  (a) K-permuted b128 frag reads: GEMM is invariant under K-permutation
//      applied to BOTH operands. New split: lane (lm,lq) reads ONE b128 at
//      intra16 = lq*256+lm*16 per unit; bytes [0,8) feed MFMA ks=0, [8,16)
//      feed ks=1 (lane presents global k=lq*16+j as mfma-k lq*8+j — same
//      bijection for A and B -> correct). 8 ds_read_b128/kt/wave replaces
//      16 ds_read_b64 (which were 4-way bank-aliased, 5.24M conflict cyc =
//      14% of kernel). Uniform bank coverage, half the addr VALU.
//      NOT bit-identical to R12 (fp32 add reorder, ~1e-6 vs 0.5 threshold).
//  (b) s_setprio(1/0) around the MFMA cluster (T5) — staging/compute
//      role-split now exists; proven +21% on phase-split schedules (m218b).
// (2nd resubmission — rounds 8-9 hit GPUAcquisitionTimeout; R13 never ran.)

#define BQ 2048
#define DD 768
#define NPASS 8
#define PP 16384
#define BM 256
#define BN 256
#define BK 64
#define KITERS 12          // 768/64
#define NBLK 64            // PP/BN
#define MBLK 8             // BQ/BM
#define NCHUNKS 256        // NBLK * 4 n-waves

#define ALPHA_C 2.6f
#define INV_2SIG2 (1.0f/6.48f)   // 1/(2*1.8^2)

typedef __attribute__((ext_vector_type(4))) float floatx4;  // MFMA C/D
typedef __attribute__((ext_vector_type(2))) long longx2;    // ds_read_b128

// ---------------------------------------------------------------------------
// Kernel 1 (fused): cast q,p -> fp8 e4m3  +  s_t exact-fp32 dots  +  out=0.
// (unchanged)
// ---------------------------------------------------------------------------
#define NQ8   196608     // 2048*768/8
#define NTOT8 1769472    // (2048+16384)*768/8
#define NCB   6912       // NTOT8/256
__global__ __launch_bounds__(256) void prep_kernel(const float* __restrict__ qf,
                                                   const float* __restrict__ pf,
                                                   uint2* __restrict__ qb,
                                                   uint2* __restrict__ pb,
                                                   float* __restrict__ st,
                                                   float* __restrict__ out) {
  const int b = blockIdx.x;
  if (b == 0 && threadIdx.x == 0) *out = 0.f;
  if (b < NCB) {
    const int i = b * 256 + threadIdx.x;        // float8 index
    const float4* src; uint2* dst;
    if (i < NQ8) { src = (const float4*)qf + 2 * (size_t)i; dst = qb + i; }
    else { const size_t j = (size_t)i - NQ8; src = (const float4*)pf + 2 * j; dst = pb + j; }
    const float4 a = src[0], c = src[1];
    unsigned lo = __builtin_amdgcn_cvt_pk_fp8_f32(a.x, a.y, 0, 0);
    lo = __builtin_amdgcn_cvt_pk_fp8_f32(a.z, a.w, lo, 1);
    unsigned hi = __builtin_amdgcn_cvt_pk_fp8_f32(c.x, c.y, 0, 0);
    hi = __builtin_amdgcn_cvt_pk_fp8_f32(c.z, c.w, hi, 1);
    uint2 w; w.x = lo; w.y = hi;
    *dst = w;
  } else {
    const int wv = threadIdx.x >> 6, lane = threadIdx.x & 63;
    const int qi = (b - NCB) * 4 + wv;
    const float4* q4 = (const float4*)(qf + (size_t)qi * DD);
    const float4* p4 = (const float4*)(pf + (size_t)qi * NPASS * DD);
    float acc = 0.f;
#pragma unroll
    for (int u = 0; u < 3; ++u) {   // 192 float4 per row = 64 lanes * 3
      float4 a = q4[lane + 64 * u];
      float4 c = p4[lane + 64 * u];
      acc = fmaf(a.x, c.x, acc);
      acc = fmaf(a.y, c.y, acc);
      acc = fmaf(a.z, c.z, acc);
      acc = fmaf(a.w, c.w, acc);
    }
#pragma unroll
    for (int off = 32; off >= 1; off >>= 1) acc += __shfl_xor(acc, off);
    if (lane == 0) st[qi] = acc;
  }
}

// ---------------------------------------------------------------------------
// Kernel 2: fp8 MFMA GEMM 256x256, BK=64, TRIPLE-buffered global_load_lds
// with counted vmcnt (R12 structure). 16 waves (4m x 4n), each wave 4x4
// MFMAs of 16x16x32 fp8_fp8 (64x64 out). LDS unit = 16 rows x 64 k-bytes =
// 1 KB, staged wave-uniform base + lane*16: unit byte = lq_s*256 + lm_s*16
// holds row lm_s, global k-bytes kt*64 + lq_s*16..+16.
// Frag read (R13): ONE ds_read_b128 per unit per lane at intra16 =
// lq*256 + lm*16 -> row lm, global k = lq*16..+16. MFMA ks=0 takes bytes
// [0,8) (global k = lq*16+j as mfma-k lq*8+j), ks=1 bytes [8,16). Same
// K-bijection for A and B -> correct dot product, K-order permuted vs R12.
// C/D: col=lane&15, row=(lane>>4)*4+reg.
// Pipeline per iter t: [vmcnt(2): own stage-t done] [s_barrier] [STAGE(t+2)
// into buf (t+2)%3 — last read at t-1, provably free] [compute buf t%3].
// ---------------------------------------------------------------------------
__global__ __launch_bounds__(1024) void gemm_kernel(const unsigned char* __restrict__ qb,
                                                    const unsigned char* __restrict__ pb,
                                                    const float* __restrict__ st,
                                                    float* __restrict__ pm,
                                                    float* __restrict__ pl,
                                                    float* __restrict__ pc) {
  __shared__ unsigned char As[3][16 * 1024];   // 48 KB
  __shared__ unsigned char Bs[3][16 * 1024];   // 48 KB
  __shared__ float st_lds[BM];

  const int t = threadIdx.x;
  const int lane = t & 63;
  const int wv = t >> 6;            // 0..15
  const int wm = wv >> 2, wn = wv & 3;
  const int bid = blockIdx.x;       // 0..511
  const int xcd = bid & 7;          // round-robin XCD assignment
  const int nb = xcd * 8 + ((bid >> 3) & 7);   // XCD-private pb slice (1.5 MB)
  const int mb = bid >> 6;          // 0..7
  const int qbase = mb * BM;
  const int n0 = nb * BN;
  const int lm = lane & 15;
  const int lq = lane >> 4;
  const int lds_lane = lane * 16;

  // st staging FIRST: its load's vmcnt is drained by the compiler before the
  // dependent ds_write, before any pipeline stages are issued.
  if (t < BM) st_lds[t] = st[qbase + t];

  floatx4 acc[4][4];
#pragma unroll
  for (int i = 0; i < 4; ++i)
#pragma unroll
    for (int j = 0; j < 4; ++j) acc[i][j] = (floatx4){0.f, 0.f, 0.f, 0.f};

  const size_t arow = (size_t)(qbase + wv * 16 + lm) * DD;
  const size_t brow = (size_t)(n0 + wv * 16 + lm) * DD;
  const int intra16 = lq * 256 + lm * 16;      // one 16-B chunk per lane

  // stage(kt, buf): 2 loads/wave (A unit wv, B unit wv), 1 KB each.
#define STAGE(KT, BUF)                                                          \
  {                                                                             \
    const size_t koff = (size_t)(KT) * BK + lq * 16;                            \
    __builtin_amdgcn_global_load_lds(                                           \
        (const __attribute__((address_space(1))) void*)(qb + arow + koff),      \
        (__attribute__((address_space(3))) void*)(&As[BUF][wv * 1024] + lds_lane), \
        16, 0, 0);                                                              \
    __builtin_amdgcn_global_load_lds(                                           \
        (const __attribute__((address_space(1))) void*)(pb + brow + koff),      \
        (__attribute__((address_space(3))) void*)(&Bs[BUF][wv * 1024] + lds_lane), \
        16, 0, 0);                                                              \
  }

  // 8 ds_read_b128 (4 A + 4 B), then 32 MFMAs under setprio(1).
  // .x = bytes [0,8) = MFMA ks=0; .y = bytes [8,16) = ks=1.
#define COMPUTE(CB)                                                             \
  {                                                                             \
    longx2 a2[4], b2[4];                                                        \
    _Pragma("unroll")                                                           \
    for (int i = 0; i < 4; ++i)                                                 \
      a2[i] = *(const longx2*)(&As[CB][(wm * 4 + i) * 1024] + intra16);         \
    _Pragma("unroll")                                                           \
    for (int j = 0; j < 4; ++j)                                                 \
      b2[j] = *(const longx2*)(&Bs[CB][(wn * 4 + j) * 1024] + intra16);         \
    __builtin_amdgcn_s_setprio(1);                                              \
    _Pragma("unroll")                                                           \
    for (int i = 0; i < 4; ++i)                                                 \
      _Pragma("unroll")                                                         \
      for (int j = 0; j < 4; ++j)                                               \
        acc[i][j] = __builtin_amdgcn_mfma_f32_16x16x32_fp8_fp8(a2[i].x, b2[j].x, acc[i][j], 0, 0, 0); \
    _Pragma("unroll")                                                           \
    for (int i = 0; i < 4; ++i)                                                 \
      _Pragma("unroll")                                                         \
      for (int j = 0; j < 4; ++j)                                               \
        acc[i][j] = __builtin_amdgcn_mfma_f32_16x16x32_fp8_fp8(a2[i].y, b2[j].y, acc[i][j], 0, 0, 0); \
    __builtin_amdgcn_s_setprio(0);                                              \
  }

  STAGE(0, 0)
  STAGE(1, 1)
  int cur = 0;            // buffer holding K-tile kt
  int stg = 2;            // buffer to stage K-tile kt+2 into
  for (int kt = 0; kt < KITERS - 1; ++kt) {
    // own stage-kt loads done (2 newest = stage kt+1 may remain in flight)
    asm volatile("s_waitcnt vmcnt(2)" ::: "memory");
    __builtin_amdgcn_s_barrier();          // all waves: stage kt complete,
    __builtin_amdgcn_sched_barrier(0);     // and all past iter kt-1 reads
    if (kt < KITERS - 2) STAGE(kt + 2, stg)
    COMPUTE(cur)
    cur = (cur == 2) ? 0 : cur + 1;
    stg = (stg == 2) ? 0 : stg + 1;
  }
  // peeled final iteration: drain the last stage
  asm volatile("s_waitcnt vmcnt(0)" ::: "memory");
  __builtin_amdgcn_s_barrier();
  __builtin_amdgcn_sched_barrier(0);
  COMPUTE(cur)

  // ---- fused epilogue: per-row (query) max / sumexp / count over 64 cols ----
  // Chunk-major partials: lanes lm==0 (lq=0..3) x r=0..3 cover 16 consecutive
  // queries -> one 64B line per (wave,i), fully dirtied within the r loop.
  const int chunk = nb * 4 + wn;
  float* const pmc = pm + (size_t)chunk * BQ;
  float* const plc = pl + (size_t)chunk * BQ;
  float* const pcc = pc + (size_t)chunk * BQ;
#pragma unroll
  for (int i = 0; i < 4; ++i) {
#pragma unroll
    for (int r = 0; r < 4; ++r) {
      const int rl = wm * 64 + i * 16 + lq * 4 + r;   // local query row
      float mx = fmaxf(fmaxf(acc[i][0][r], acc[i][1][r]),
                       fmaxf(acc[i][2][r], acc[i][3][r]));
#pragma unroll
      for (int off = 1; off <= 8; off <<= 1) mx = fmaxf(mx, __shfl_xor(mx, off));
      const float stv = st_lds[rl];
      const int qg = qbase + rl;
      const int tcol = qg * NPASS;
      float sum = 0.f, c = 0.f;
#pragma unroll
      for (int j = 0; j < 4; ++j) {
        const float s = acc[i][j][r];
        sum += __expf(s - mx);
        const int cg = n0 + wn * 64 + j * 16 + lm;
        if (s > stv && cg != tcol) c += 1.f;
      }
#pragma unroll
      for (int off = 1; off <= 8; off <<= 1) {
        sum += __shfl_xor(sum, off);
        c += __shfl_xor(c, off);
      }
      if (lm == 0) {
        pmc[qg] = mx; plc[qg] = sum; pcc[qg] = c;
      }
    }
  }
}

// ---------------------------------------------------------------------------
// Kernel 3: merge 256 chunks/query (chunk-major partials), weighted CE, mean.
// 32 blocks x 256 thr; block owns 64 queries; wave wv owns chunks wv*64..+63.
// Loads coalesced across q (lane = q within block). Online max-merge.
// ---------------------------------------------------------------------------
__global__ __launch_bounds__(256) void finalize_kernel(const float* __restrict__ st,
                                                       const float* __restrict__ pm,
                                                       const float* __restrict__ pl,
                                                       const float* __restrict__ pc,
                                                       float* __restrict__ out) {
  const int wv = threadIdx.x >> 6, lane = threadIdx.x & 63;
  const int q = blockIdx.x * 64 + lane;
  const int c0 = wv * 64;
  float m = -1e30f, l = 0.f, c = 0.f;
#pragma unroll 4
  for (int ch = 0; ch < 64; ++ch) {
    const size_t idx = (size_t)(c0 + ch) * BQ + q;
    const float mv = pm[idx], lv = pl[idx], cv = pc[idx];
    const float nm = fmaxf(m, mv);
    l = l * __expf(m - nm) + lv * __expf(mv - nm);
    m = nm; c += cv;
  }
  __shared__ float sm[4][64], sl[4][64], sc[4][64];
  sm[wv][lane] = m; sl[wv][lane] = l; sc[wv][lane] = c;
  __syncthreads();
  if (wv == 0) {
    float M = sm[0][lane], L = sl[0][lane], C = sc[0][lane];
#pragma unroll
    for (int w = 1; w < 4; ++w) {
      const float mv = sm[w][lane];
      const float nm = fmaxf(M, mv);
      L = L * __expf(M - nm) + sl[w][lane] * __expf(mv - nm);
      M = nm; C += sc[w][lane];
    }
    const float raw = logf(L) + M - st[q];     // -log_softmax[target]
    const float dr = C - 1.0f;                 // rank - OPTIMAL_RANK
    const float w = 1.0f + ALPHA_C * __expf(-(dr * dr) * INV_2SIG2);
    float loss = raw * w * (1.0f / (float)BQ);
#pragma unroll
    for (int off = 32; off >= 1; off >>= 1) loss += __shfl_xor(loss, off);
    if (lane == 0) atomicAdd(out, loss);
  }
}

// ---------------------------------------------------------------------------
extern "C" void kernel_launch(void* const* d_in, const int* in_sizes, int n_in,
                              void* d_out, int out_size, void* d_ws, size_t ws_size,
                              hipStream_t stream) {
  const float* q = (const float*)d_in[0];
  const float* p = (const float*)d_in[1];
  char* ws = (char*)d_ws;
  unsigned char* qb = (unsigned char*)ws;                  // 1,572,864 B
  unsigned char* pb = (unsigned char*)(ws + 1572864);      // 12,582,912 B
  float* st = (float*)(ws + 14155776);                     // 8 KB
  float* pm = (float*)(ws + 14163968);                     // 2 MB
  float* pl = (float*)(ws + 16261120);                     // 2 MB
  float* pc = (float*)(ws + 18358272);                     // 2 MB (end ~20.5 MB)
  float* out = (float*)d_out;

  prep_kernel<<<NCB + BQ / 4, 256, 0, stream>>>(q, p, (uint2*)qb, (uint2*)pb, st, out);
  gemm_kernel<<<NBLK * MBLK, 1024, 0, stream>>>(qb, pb, st, pm, pl, pc);
  finalize_kernel<<<BQ / 64, 256, 0, stream>>>(st, pm, pl, pc, out);
}

// Round 12
// 152.849 us; speedup vs baseline: 1.0023x; 1.0023x over previous
//
#include <hip/hip_runtime.h>
#include <math.h>

// Problem: scores = q[2048x768] @ p[16384x768]^T (fp32 in), per-query
// rank-of-target + log-softmax CE + Gaussian rank weight -> mean (scalar).
// R14 = R13 with ONE change: intra-iter read||MFMA interleave in COMPUTE.
// R13 post-mortem: b128 K-permuted reads -> BANK_CONFLICT 5.24M -> 0 but
// gemm 60.3 -> 59.5 (flat), MfmaUtil stuck 33%. Falsifier branch taken:
// LDS reads weren't the critical path; the per-iter convoy is (all 16
// waves storm-read together while MFMA idles, then all compute while LDS
// idles -> both pipes ~33%). Fix (m196 mechanism, no sync change):
// 3-phase COMPUTE with sched_barrier(0) pins:
//   read a01,b01 | read b23 | MFMA(i01,j01)x8   <- b23 hides under MFMAs
//   | read a23   | MFMA(i01,j23)x8              <- a23 hides under MFMAs
//   | MFMA(i23,*)x16
// Compiler emits counted lgkmcnt(2) instead of batch-wait; waves stagger
// across phases -> LDS and MFMA pipes co-run. Barriers/vmcnt/buffers
// UNTOUCHED -> race-impossible, same per-acc MFMA order (absmax 0.5).
// Prediction: MfmaUtil 33->38-44, gemm 59.5->~50-53, total ~145.
// If flat: convoy is the barrier itself -> R15 = 8-phase port or MX 32x32.
// (Resubmission — round 11 hit GPUAcquisitionTimeout; R14 never ran.)

#define BQ 2048
#define DD 768
#define NPASS 8
#define PP 16384
#define BM 256
#define BN 256
#define BK 64
#define KITERS 12          // 768/64
#define NBLK 64            // PP/BN
#define MBLK 8             // BQ/BM
#define NCHUNKS 256        // NBLK * 4 n-waves

#define ALPHA_C 2.6f
#define INV_2SIG2 (1.0f/6.48f)   // 1/(2*1.8^2)

typedef __attribute__((ext_vector_type(4))) float floatx4;  // MFMA C/D
typedef __attribute__((ext_vector_type(2))) long longx2;    // ds_read_b128

// ---------------------------------------------------------------------------
// Kernel 1 (fused): cast q,p -> fp8 e4m3  +  s_t exact-fp32 dots  +  out=0.
// (unchanged)
// ---------------------------------------------------------------------------
#define NQ8   196608     // 2048*768/8
#define NTOT8 1769472    // (2048+16384)*768/8
#define NCB   6912       // NTOT8/256
__global__ __launch_bounds__(256) void prep_kernel(const float* __restrict__ qf,
                                                   const float* __restrict__ pf,
                                                   uint2* __restrict__ qb,
                                                   uint2* __restrict__ pb,
                                                   float* __restrict__ st,
                                                   float* __restrict__ out) {
  const int b = blockIdx.x;
  if (b == 0 && threadIdx.x == 0) *out = 0.f;
  if (b < NCB) {
    const int i = b * 256 + threadIdx.x;        // float8 index
    const float4* src; uint2* dst;
    if (i < NQ8) { src = (const float4*)qf + 2 * (size_t)i; dst = qb + i; }
    else { const size_t j = (size_t)i - NQ8; src = (const float4*)pf + 2 * j; dst = pb + j; }
    const float4 a = src[0], c = src[1];
    unsigned lo = __builtin_amdgcn_cvt_pk_fp8_f32(a.x, a.y, 0, 0);
    lo = __builtin_amdgcn_cvt_pk_fp8_f32(a.z, a.w, lo, 1);
    unsigned hi = __builtin_amdgcn_cvt_pk_fp8_f32(c.x, c.y, 0, 0);
    hi = __builtin_amdgcn_cvt_pk_fp8_f32(c.z, c.w, hi, 1);
    uint2 w; w.x = lo; w.y = hi;
    *dst = w;
  } else {
    const int wv = threadIdx.x >> 6, lane = threadIdx.x & 63;
    const int qi = (b - NCB) * 4 + wv;
    const float4* q4 = (const float4*)(qf + (size_t)qi * DD);
    const float4* p4 = (const float4*)(pf + (size_t)qi * NPASS * DD);
    float acc = 0.f;
#pragma unroll
    for (int u = 0; u < 3; ++u) {   // 192 float4 per row = 64 lanes * 3
      float4 a = q4[lane + 64 * u];
      float4 c = p4[lane + 64 * u];
      acc = fmaf(a.x, c.x, acc);
      acc = fmaf(a.y, c.y, acc);
      acc = fmaf(a.z, c.z, acc);
      acc = fmaf(a.w, c.w, acc);
    }
#pragma unroll
    for (int off = 32; off >= 1; off >>= 1) acc += __shfl_xor(acc, off);
    if (lane == 0) st[qi] = acc;
  }
}

// ---------------------------------------------------------------------------
// Kernel 2: fp8 MFMA GEMM 256x256, BK=64, TRIPLE-buffered global_load_lds
// with counted vmcnt (R12 structure). 16 waves (4m x 4n), each wave 4x4
// MFMAs of 16x16x32 fp8_fp8 (64x64 out). LDS unit = 16 rows x 64 k-bytes =
// 1 KB, staged wave-uniform base + lane*16: unit byte = lq_s*256 + lm_s*16
// holds row lm_s, global k-bytes kt*64 + lq_s*16..+16.
// Frag read (R13, conflict-free verified): ONE ds_read_b128 per unit per
// lane at intra16 = lq*256 + lm*16 -> row lm, global k = lq*16..+16.
// MFMA ks=0 takes bytes [0,8), ks=1 bytes [8,16); same K-bijection for A
// and B -> correct dot product. C/D: col=lane&15, row=(lane>>4)*4+reg.
// Pipeline per iter t: [vmcnt(2): own stage-t done] [s_barrier] [STAGE(t+2)
// into buf (t+2)%3 — last read at t-1, provably free] [3-phase interleaved
// compute of buf t%3 (R14)].
// ---------------------------------------------------------------------------
__global__ __launch_bounds__(1024) void gemm_kernel(const unsigned char* __restrict__ qb,
                                                    const unsigned char* __restrict__ pb,
                                                    const float* __restrict__ st,
                                                    float* __restrict__ pm,
                                                    float* __restrict__ pl,
                                                    float* __restrict__ pc) {
  __shared__ unsigned char As[3][16 * 1024];   // 48 KB
  __shared__ unsigned char Bs[3][16 * 1024];   // 48 KB
  __shared__ float st_lds[BM];

  const int t = threadIdx.x;
  const int lane = t & 63;
  const int wv = t >> 6;            // 0..15
  const int wm = wv >> 2, wn = wv & 3;
  const int bid = blockIdx.x;       // 0..511
  const int xcd = bid & 7;          // round-robin XCD assignment
  const int nb = xcd * 8 + ((bid >> 3) & 7);   // XCD-private pb slice (1.5 MB)
  const int mb = bid >> 6;          // 0..7
  const int qbase = mb * BM;
  const int n0 = nb * BN;
  const int lm = lane & 15;
  const int lq = lane >> 4;
  const int lds_lane = lane * 16;

  // st staging FIRST: its load's vmcnt is drained by the compiler before the
  // dependent ds_write, before any pipeline stages are issued.
  if (t < BM) st_lds[t] = st[qbase + t];

  floatx4 acc[4][4];
#pragma unroll
  for (int i = 0; i < 4; ++i)
#pragma unroll
    for (int j = 0; j < 4; ++j) acc[i][j] = (floatx4){0.f, 0.f, 0.f, 0.f};

  const size_t arow = (size_t)(qbase + wv * 16 + lm) * DD;
  const size_t brow = (size_t)(n0 + wv * 16 + lm) * DD;
  const int intra16 = lq * 256 + lm * 16;      // one 16-B chunk per lane

  // stage(kt, buf): 2 loads/wave (A unit wv, B unit wv), 1 KB each.
#define STAGE(KT, BUF)                                                          \
  {                                                                             \
    const size_t koff = (size_t)(KT) * BK + lq * 16;                            \
    __builtin_amdgcn_global_load_lds(                                           \
        (const __attribute__((address_space(1))) void*)(qb + arow + koff),      \
        (__attribute__((address_space(3))) void*)(&As[BUF][wv * 1024] + lds_lane), \
        16, 0, 0);                                                              \
    __builtin_amdgcn_global_load_lds(                                           \
        (const __attribute__((address_space(1))) void*)(pb + brow + koff),      \
        (__attribute__((address_space(3))) void*)(&Bs[BUF][wv * 1024] + lds_lane), \
        16, 0, 0);                                                              \
  }

  // 8 MFMAs for (i-pair II, j-pair JJ): 4 acc tiles x 2 ks, ks-split so the
  // dependent same-acc pair is 4 apart (no back-to-back acc dependency).
#define MFMA8(II, JJ)                                                           \
  {                                                                             \
    acc[II][JJ]       = __builtin_amdgcn_mfma_f32_16x16x32_fp8_fp8(a2[II].x,     b2[JJ].x,     acc[II][JJ],       0, 0, 0); \
    acc[II][JJ+1]     = __builtin_amdgcn_mfma_f32_16x16x32_fp8_fp8(a2[II].x,     b2[JJ+1].x,   acc[II][JJ+1],     0, 0, 0); \
    acc[II+1][JJ]     = __builtin_amdgcn_mfma_f32_16x16x32_fp8_fp8(a2[II+1].x,   b2[JJ].x,     acc[II+1][JJ],     0, 0, 0); \
    acc[II+1][JJ+1]   = __builtin_amdgcn_mfma_f32_16x16x32_fp8_fp8(a2[II+1].x,   b2[JJ+1].x,   acc[II+1][JJ+1],   0, 0, 0); \
    acc[II][JJ]       = __builtin_amdgcn_mfma_f32_16x16x32_fp8_fp8(a2[II].y,     b2[JJ].y,     acc[II][JJ],       0, 0, 0); \
    acc[II][JJ+1]     = __builtin_amdgcn_mfma_f32_16x16x32_fp8_fp8(a2[II].y,     b2[JJ+1].y,   acc[II][JJ+1],     0, 0, 0); \
    acc[II+1][JJ]     = __builtin_amdgcn_mfma_f32_16x16x32_fp8_fp8(a2[II+1].y,   b2[JJ].y,     acc[II+1][JJ],     0, 0, 0); \
    acc[II+1][JJ+1]   = __builtin_amdgcn_mfma_f32_16x16x32_fp8_fp8(a2[II+1].y,   b2[JJ+1].y,   acc[II+1][JJ+1],   0, 0, 0); \
  }

  // R14 3-phase interleaved compute: reads for phase p+1 issue BEFORE phase
  // p's MFMAs (sched_barrier(0) pins); compiler emits counted lgkmcnt.
#define COMPUTE(CB)                                                             \
  {                                                                             \
    longx2 a2[4], b2[4];                                                        \
    a2[0] = *(const longx2*)(&As[CB][(wm * 4 + 0) * 1024] + intra16);           \
    a2[1] = *(const longx2*)(&As[CB][(wm * 4 + 1) * 1024] + intra16);           \
    b2[0] = *(const longx2*)(&Bs[CB][(wn * 4 + 0) * 1024] + intra16);           \
    b2[1] = *(const longx2*)(&Bs[CB][(wn * 4 + 1) * 1024] + intra16);           \
    __builtin_amdgcn_sched_barrier(0);                                          \
    b2[2] = *(const longx2*)(&Bs[CB][(wn * 4 + 2) * 1024] + intra16);           \
    b2[3] = *(const longx2*)(&Bs[CB][(wn * 4 + 3) * 1024] + intra16);           \
    __builtin_amdgcn_sched_barrier(0);                                          \
    __builtin_amdgcn_s_setprio(1);                                              \
    MFMA8(0, 0)                                                                 \
    __builtin_amdgcn_s_setprio(0);                                              \
    __builtin_amdgcn_sched_barrier(0);                                          \
    a2[2] = *(const longx2*)(&As[CB][(wm * 4 + 2) * 1024] + intra16);           \
    a2[3] = *(const longx2*)(&As[CB][(wm * 4 + 3) * 1024] + intra16);           \
    __builtin_amdgcn_sched_barrier(0);                                          \
    __builtin_amdgcn_s_setprio(1);                                              \
    MFMA8(0, 2)                                                                 \
    __builtin_amdgcn_s_setprio(0);                                              \
    __builtin_amdgcn_sched_barrier(0);                                          \
    __builtin_amdgcn_s_setprio(1);                                              \
    MFMA8(2, 0)                                                                 \
    MFMA8(2, 2)                                                                 \
    __builtin_amdgcn_s_setprio(0);                                              \
  }

  STAGE(0, 0)
  STAGE(1, 1)
  int cur = 0;            // buffer holding K-tile kt
  int stg = 2;            // buffer to stage K-tile kt+2 into
  for (int kt = 0; kt < KITERS - 1; ++kt) {
    // own stage-kt loads done (2 newest = stage kt+1 may remain in flight)
    asm volatile("s_waitcnt vmcnt(2)" ::: "memory");
    __builtin_amdgcn_s_barrier();          // all waves: stage kt complete,
    __builtin_amdgcn_sched_barrier(0);     // and all past iter kt-1 reads
    if (kt < KITERS - 2) STAGE(kt + 2, stg)
    COMPUTE(cur)
    cur = (cur == 2) ? 0 : cur + 1;
    stg = (stg == 2) ? 0 : stg + 1;
  }
  // peeled final iteration: drain the last stage
  asm volatile("s_waitcnt vmcnt(0)" ::: "memory");
  __builtin_amdgcn_s_barrier();
  __builtin_amdgcn_sched_barrier(0);
  COMPUTE(cur)

  // ---- fused epilogue: per-row (query) max / sumexp / count over 64 cols ----
  // Chunk-major partials: lanes lm==0 (lq=0..3) x r=0..3 cover 16 consecutive
  // queries -> one 64B line per (wave,i), fully dirtied within the r loop.
  const int chunk = nb * 4 + wn;
  float* const pmc = pm + (size_t)chunk * BQ;
  float* const plc = pl + (size_t)chunk * BQ;
  float* const pcc = pc + (size_t)chunk * BQ;
#pragma unroll
  for (int i = 0; i < 4; ++i) {
#pragma unroll
    for (int r = 0; r < 4; ++r) {
      const int rl = wm * 64 + i * 16 + lq * 4 + r;   // local query row
      float mx = fmaxf(fmaxf(acc[i][0][r], acc[i][1][r]),
                       fmaxf(acc[i][2][r], acc[i][3][r]));
#pragma unroll
      for (int off = 1; off <= 8; off <<= 1) mx = fmaxf(mx, __shfl_xor(mx, off));
      const float stv = st_lds[rl];
      const int qg = qbase + rl;
      const int tcol = qg * NPASS;
      float sum = 0.f, c = 0.f;
#pragma unroll
      for (int j = 0; j < 4; ++j) {
        const float s = acc[i][j][r];
        sum += __expf(s - mx);
        const int cg = n0 + wn * 64 + j * 16 + lm;
        if (s > stv && cg != tcol) c += 1.f;
      }
#pragma unroll
      for (int off = 1; off <= 8; off <<= 1) {
        sum += __shfl_xor(sum, off);
        c += __shfl_xor(c, off);
      }
      if (lm == 0) {
        pmc[qg] = mx; plc[qg] = sum; pcc[qg] = c;
      }
    }
  }
}

// ---------------------------------------------------------------------------
// Kernel 3: merge 256 chunks/query (chunk-major partials), weighted CE, mean.
// 32 blocks x 256 thr; block owns 64 queries; wave wv owns chunks wv*64..+63.
// Loads coalesced across q (lane = q within block). Online max-merge.
// ---------------------------------------------------------------------------
__global__ __launch_bounds__(256) void finalize_kernel(const float* __restrict__ st,
                                                       const float* __restrict__ pm,
                                                       const float* __restrict__ pl,
                                                       const float* __restrict__ pc,
                                                       float* __restrict__ out) {
  const int wv = threadIdx.x >> 6, lane = threadIdx.x & 63;
  const int q = blockIdx.x * 64 + lane;
  const int c0 = wv * 64;
  float m = -1e30f, l = 0.f, c = 0.f;
#pragma unroll 4
  for (int ch = 0; ch < 64; ++ch) {
    const size_t idx = (size_t)(c0 + ch) * BQ + q;
    const float mv = pm[idx], lv = pl[idx], cv = pc[idx];
    const float nm = fmaxf(m, mv);
    l = l * __expf(m - nm) + lv * __expf(mv - nm);
    m = nm; c += cv;
  }
  __shared__ float sm[4][64], sl[4][64], sc[4][64];
  sm[wv][lane] = m; sl[wv][lane] = l; sc[wv][lane] = c;
  __syncthreads();
  if (wv == 0) {
    float M = sm[0][lane], L = sl[0][lane], C = sc[0][lane];
#pragma unroll
    for (int w = 1; w < 4; ++w) {
      const float mv = sm[w][lane];
      const float nm = fmaxf(M, mv);
      L = L * __expf(M - nm) + sl[w][lane] * __expf(mv - nm);
      M = nm; C += sc[w][lane];
    }
    const float raw = logf(L) + M - st[q];     // -log_softmax[target]
    const float dr = C - 1.0f;                 // rank - OPTIMAL_RANK
    const float w = 1.0f + ALPHA_C * __expf(-(dr * dr) * INV_2SIG2);
    float loss = raw * w * (1.0f / (float)BQ);
#pragma unroll
    for (int off = 32; off >= 1; off >>= 1) loss += __shfl_xor(loss, off);
    if (lane == 0) atomicAdd(out, loss);
  }
}

// ---------------------------------------------------------------------------
extern "C" void kernel_launch(void* const* d_in, const int* in_sizes, int n_in,
                              void* d_out, int out_size, void* d_ws, size_t ws_size,
                              hipStream_t stream) {
  const float* q = (const float*)d_in[0];
  const float* p = (const float*)d_in[1];
  char* ws = (char*)d_ws;
  unsigned char* qb = (unsigned char*)ws;                  // 1,572,864 B
  unsigned char* pb = (unsigned char*)(ws + 1572864);      // 12,582,912 B
  float* st = (float*)(ws + 14155776);                     // 8 KB
  float* pm = (float*)(ws + 14163968);                     // 2 MB
  float* pl = (float*)(ws + 16261120);                     // 2 MB
  float* pc = (float*)(ws + 18358272);                     // 2 MB (end ~20.5 MB)
  float* out = (float*)d_out;

  prep_kernel<<<NCB + BQ / 4, 256, 0, stream>>>(q, p, (uint2*)qb, (uint2*)pb, st, out);
  gemm_kernel<<<NBLK * MBLK, 1024, 0, stream>>>(qb, pb, st, pm, pl, pc);
  finalize_kernel<<<BQ / 64, 256, 0, stream>>>(st, pm, pl, pc, out);
}